// Round 4
// baseline (689.146 us; speedup 1.0000x reference)
//
#include <hip/hip_runtime.h>

#define D 2048
#define KPAD 160
#define PSTR 168
#define XSTR 2072
#define MTILE 16
#define THREADS 1024
#define NTILES 8

typedef __attribute__((ext_vector_type(8))) short bf16x8;
typedef __attribute__((ext_vector_type(4))) float f32x4;

__device__ inline unsigned short f2bf(float f) {
  unsigned int u = __float_as_uint(f);
  u += 0x7fffu + ((u >> 16) & 1u);   // round-to-nearest-even
  return (unsigned short)(u >> 16);
}
__device__ inline float bf2f(unsigned short h) {
  return __uint_as_float(((unsigned int)h) << 16);
}

// raw barrier: LDS visibility only — NO vmcnt drain (keeps loads/stores in flight)
__device__ inline void wg_barrier() {
  asm volatile("s_waitcnt lgkmcnt(0)" ::: "memory");
  __builtin_amdgcn_s_barrier();
}

// ---- prep: pack Wp|Wv -> Wpv_t[32][2048] bf16 (n-major, k contiguous) ----
__global__ __launch_bounds__(256) void prep_wpv(const float* __restrict__ Wp,
                                                const float* __restrict__ Wv,
                                                unsigned short* __restrict__ Wpvt) {
  int idx = blockIdx.x * 256 + threadIdx.x;
  int n = idx >> 11, k = idx & 2047;
  float v = 0.f;
  if (n < 12) v = Wp[k * 12 + n];
  else if (n < 24) v = Wv[k * 12 + (n - 12)];
  Wpvt[idx] = f2bf(v);
}

// ---- prep: Wi[144][2048] -> Wi_t[2048][160] bf16 ----
__global__ __launch_bounds__(256) void prep_wi(const float* __restrict__ Wi,
                                               unsigned short* __restrict__ Wit) {
  int idx = blockIdx.x * 256 + threadIdx.x;
  int n = idx / KPAD, k = idx - n * KPAD;
  float v = (k < 144) ? Wi[k * 2048 + n] : 0.f;
  Wit[idx] = f2bf(v);
}

// ---- fused, persistent-ish: 1 block/CU, 8 row-tiles, software-pipelined ----
// LDS: xt 66304 + sred 18432 + sP 5376 + spart 2048 + sstat 128 + params 24672 = ~117 KB
__global__ __launch_bounds__(THREADS, 4) void gil_fused(
    const float* __restrict__ x, const float* __restrict__ bp,
    const float* __restrict__ bv, const float* __restrict__ bi,
    const float* __restrict__ gamma, const float* __restrict__ beta,
    const unsigned short* __restrict__ Wpvt, const unsigned short* __restrict__ Wit,
    float* __restrict__ out) {
  __shared__ unsigned short xt[MTILE][XSTR];      // x tile (bf16)
  __shared__ float sred[8][MTILE][36];            // phase-1 K-partials
  __shared__ __align__(16) unsigned short sP[MTILE][PSTR];
  __shared__ float spart[16][MTILE][2];
  __shared__ float sstat[MTILE][2];
  __shared__ float sbi[D], sg[D], sb[D];
  __shared__ float sbp_[12], sbv_[12];

  const int t = threadIdx.x;
  const int wave = t >> 6, lane = t & 63;
  const int lm = lane & 15, quad = lane >> 4;
  const int pr = t >> 6;            // prefetch row (== wave)
  const int pc = (t & 63) * 4;      // prefetch col base
  const int rowbase0 = blockIdx.x * (MTILE * NTILES);

  // ---- prologue: params -> LDS; stage tile 0 ----
  for (int j = t; j < D; j += THREADS) { sbi[j] = bi[j]; sg[j] = gamma[j]; sb[j] = beta[j]; }
  if (t < 12) { sbp_[t] = bp[t]; sbv_[t] = bv[t]; }
  {
    const float* xp = x + (size_t)(rowbase0 + pr) * D + pc;
    f32x4 p0[8];
#pragma unroll
    for (int j = 0; j < 8; ++j) p0[j] = *(const f32x4*)(xp + j * 256);
#pragma unroll
    for (int j = 0; j < 8; ++j) {
      ushort4 u;
      u.x = f2bf(p0[j][0]); u.y = f2bf(p0[j][1]);
      u.z = f2bf(p0[j][2]); u.w = f2bf(p0[j][3]);
      *(ushort4*)&xt[pr][pc + j * 256] = u;
    }
  }

#pragma unroll 1
  for (int it = 0; it < NTILES; ++it) {
    const int rb = rowbase0 + it * MTILE;
    wg_barrier();                                 // B1: xt ready, sred free

    // ---- phase 1: pos|vel partials; wave -> (nt, K-slice of 256) ----
    {
      int nt = wave & 1, ks = wave >> 1;
      f32x4 acc = {0.f, 0.f, 0.f, 0.f};
      const unsigned short* bptr = Wpvt + (size_t)(nt * 16 + lm) * D + ks * 256;
#pragma unroll
      for (int kk = 0; kk < 8; ++kk) {
        int k0 = kk * 32 + quad * 8;
        bf16x8 a = *(const bf16x8*)&xt[lm][ks * 256 + k0];
        bf16x8 b = *(const bf16x8*)(bptr + k0);
        acc = __builtin_amdgcn_mfma_f32_16x16x32_bf16(a, b, acc, 0, 0, 0);
      }
#pragma unroll
      for (int rg = 0; rg < 4; ++rg)
        sred[ks][quad * 4 + rg][nt * 16 + lm] = acc[rg];
    }
    wg_barrier();                                 // B2: sred ready

    // ---- phase 1b: 8-way K-reduce + bias; outer product -> sP ----
    if (t < 512) {
      int m = t >> 5, n = t & 31;
      float pv = 0.f;
#pragma unroll
      for (int w2 = 0; w2 < 8; ++w2) pv += sred[w2][m][n];
      if (n < 12) pv += sbp_[n];
      else if (n < 24) pv += sbv_[n - 12];
#pragma unroll
      for (int kk = 0; kk < 5; ++kk) {
        int k = n + 32 * kk;
        int i = k / 12, j = k - i * 12;
        float a = __shfl(pv, i, 32);
        float b = __shfl(pv, 12 + j, 32);
        sP[m][k] = f2bf((k < 144) ? a * b : 0.f);
      }
    }
    wg_barrier();                                 // B3: sP ready

    // ---- phase 2: inter^T = Wi_rows x P; each wave owns 128 cols ----
    f32x4 accv[8];
    {
      bf16x8 af[5];
#pragma unroll
      for (int kc = 0; kc < 5; ++kc)
        af[kc] = *(const bf16x8*)&sP[lm][kc * 32 + quad * 8];
#pragma unroll
      for (int nt2 = 0; nt2 < 8; ++nt2) {
        const unsigned short* wb = Wit + (size_t)(wave * 128 + nt2 * 16 + lm) * KPAD;
        f32x4 acc = {0.f, 0.f, 0.f, 0.f};
#pragma unroll
        for (int kc = 0; kc < 5; ++kc) {
          bf16x8 wv = *(const bf16x8*)(wb + kc * 32 + quad * 8);
          acc = __builtin_amdgcn_mfma_f32_16x16x32_bf16(wv, af[kc], acc, 0, 0, 0);
        }
        accv[nt2] = acc;
      }
    }

    // ---- issue next-tile x prefetch AFTER Wit loads (in-order vmcnt!) ----
    __builtin_amdgcn_sched_barrier(0);
    const bool havepf = (it + 1 < NTILES);
    f32x4 pf[8];
    if (havepf) {
      const float* xp = x + (size_t)(rb + MTILE + pr) * D + pc;
#pragma unroll
      for (int j = 0; j < 8; ++j) pf[j] = *(const f32x4*)(xp + j * 256);
    }

    // ---- phase 3a: y = x + inter + bi (all LDS-sourced); LN partials ----
    float s = 0.f, ss = 0.f;
    const int dbase = wave * 128;
#pragma unroll
    for (int nt2 = 0; nt2 < 8; ++nt2) {
      int d0 = dbase + nt2 * 16 + quad * 4;
      f32x4 bi4 = *(const f32x4*)&sbi[d0];
      ushort4 xv = *(const ushort4*)&xt[lm][d0];
      float xf0 = bf2f(xv.x), xf1 = bf2f(xv.y), xf2 = bf2f(xv.z), xf3 = bf2f(xv.w);
      float y0 = accv[nt2][0] + bi4[0] + xf0;
      float y1 = accv[nt2][1] + bi4[1] + xf1;
      float y2 = accv[nt2][2] + bi4[2] + xf2;
      float y3 = accv[nt2][3] + bi4[3] + xf3;
      accv[nt2][0] = y0; accv[nt2][1] = y1; accv[nt2][2] = y2; accv[nt2][3] = y3;
      s += y0 + y1 + y2 + y3;
      ss += y0 * y0 + y1 * y1 + y2 * y2 + y3 * y3;
    }
    s += __shfl_xor(s, 16); ss += __shfl_xor(ss, 16);
    s += __shfl_xor(s, 32); ss += __shfl_xor(ss, 32);
    if (lane < 16) { spart[wave][lm][0] = s; spart[wave][lm][1] = ss; }
    wg_barrier();                                 // B4: spart ready, xt free

    if (t < MTILE) {
      float su = 0.f, sq = 0.f;
#pragma unroll
      for (int w2 = 0; w2 < 16; ++w2) { su += spart[w2][t][0]; sq += spart[w2][t][1]; }
      float mu = su * (1.f / D);
      float var = sq * (1.f / D) - mu * mu;
      sstat[t][0] = mu;
      sstat[t][1] = rsqrtf(var + 1e-5f);
    }
    wg_barrier();                                 // B5: sstat ready

    // ---- write next x tile into LDS (waits pf loads only) ----
    if (havepf) {
#pragma unroll
      for (int j = 0; j < 8; ++j) {
        ushort4 u;
        u.x = f2bf(pf[j][0]); u.y = f2bf(pf[j][1]);
        u.z = f2bf(pf[j][2]); u.w = f2bf(pf[j][3]);
        *(ushort4*)&xt[pr][pc + j * 256] = u;
      }
    }

    // ---- phase 3b: normalize + float4 stores (drain across tiles) ----
    {
      float mu = sstat[lm][0], rs = sstat[lm][1];
      float* orow = out + (size_t)(rb + lm) * D;
#pragma unroll
      for (int nt2 = 0; nt2 < 8; ++nt2) {
        int d0 = dbase + nt2 * 16 + quad * 4;
        f32x4 g4 = *(const f32x4*)&sg[d0];
        f32x4 b4 = *(const f32x4*)&sb[d0];
        f32x4 o;
#pragma unroll
        for (int rg = 0; rg < 4; ++rg)
          o[rg] = (accv[nt2][rg] - mu) * rs * g4[rg] + b4[rg];
        *(f32x4*)(orow + d0) = o;
      }
    }
  }
}

extern "C" void kernel_launch(void* const* d_in, const int* in_sizes, int n_in,
                              void* d_out, int out_size, void* d_ws, size_t ws_size,
                              hipStream_t stream) {
  const float* x     = (const float*)d_in[0];
  const float* Wp    = (const float*)d_in[1];
  const float* bp    = (const float*)d_in[2];
  const float* Wv    = (const float*)d_in[3];
  const float* bv    = (const float*)d_in[4];
  const float* Wi    = (const float*)d_in[5];
  const float* bi    = (const float*)d_in[6];
  const float* gamma = (const float*)d_in[7];
  const float* beta  = (const float*)d_in[8];
  float* out = (float*)d_out;

  unsigned short* Wpvt = (unsigned short*)d_ws;               // 32*2048 bf16
  unsigned short* Wit  = Wpvt + 32 * 2048;                    // 2048*160 bf16

  prep_wpv<<<(32 * 2048) / 256, 256, 0, stream>>>(Wp, Wv, Wpvt);
  prep_wi<<<(2048 * KPAD) / 256, 256, 0, stream>>>(Wi, Wit);

  int rows = in_sizes[0] / D;                                  // 32768
  int tiles = rows / MTILE;                                    // 2048
  gil_fused<<<tiles / NTILES, THREADS, 0, stream>>>(x, bp, bv, bi, gamma, beta,
                                                    Wpvt, Wit, out);
}